// Round 4
// baseline (1439.105 us; speedup 1.0000x reference)
//
#include <hip/hip_runtime.h>
#include <hip/hip_bf16.h>

// Problem constants (from reference): B=64, NCLS=200 -> BN rows = 12800
#define BROWS  12800
#define TSTEPS 8
#define EMB    300
#define EMBP   320          // EMB padded to /32 for MFMA K
#define RNN    512
#define NG     2048         // 4*RNN gate width
#define K1     832          // EMBP + RNN  (layer-1 concat GEMM K), 26*32
#define K132   26
#define K2     1024         // RNN + RNN   (layer-2 concat GEMM K), 32*32
#define K232   32

typedef short bf16x8 __attribute__((ext_vector_type(8)));   // 8 bf16 in 4 VGPRs (m89-verified operand type)
typedef float f32x4  __attribute__((ext_vector_type(4)));
typedef __hip_bfloat16 bf16;

__device__ __forceinline__ float sigmoidf_(float x) { return 1.f / (1.f + __expf(-x)); }
// exp-based tanh: exact saturation at +-inf, ~ulp-level error vs tanhf, one v_exp
__device__ __forceinline__ float tanhf_(float x)    { return 1.f - 2.f / (__expf(2.f * x) + 1.f); }

// ---------------------------------------------------------------------------
// TILED OPERAND LAYOUT ("MFMA-fragment order"):
// a [16 rows x 32 k] subtile is stored as 512 contiguous bf16 (1024 B) such
// that lane l = 16*q + r reads its 8 elements [m=r][k=q*8+j] at byte l*16.
// T(row,col,K32) = ((row>>4)*K32 + (col>>5))*512 + ((col>>3)&3)*128
//                  + (row&15)*8 + (col&7)
// One MFMA fragment = one fully-coalesced 1024B global_load_dwordx4 wave-op.
// This matches the m89/m91-HW-verified 16x16x32 A/B operand lane layout that
// round-3's LDS reads used (m=lane&15, k=(lane>>4)*8+j).
// ---------------------------------------------------------------------------
__device__ __forceinline__ int tidx(int row, int col, int K32) {
    return (((row >> 4) * K32 + (col >> 5)) << 9) + (((col >> 3) & 3) << 7)
           + ((row & 15) << 3) + (col & 7);
}

// ---------------------------------------------------------------------------
// Weight repack: fp32 -> bf16, K-concat, GATE-INTERLEAVED row permutation
// (output row n: w=n&15 unit, g=(n>>4)&3 gate i/f/g/o, b=n>>6 unit group;
// original row = g*512 + b*16 + w), stored in TILED layout. Also emits
// permuted combined biases Bp = bih+bhh.
// ---------------------------------------------------------------------------
__global__ void convert_weights(const float* __restrict__ Wih1, const float* __restrict__ Whh1,
                                const float* __restrict__ Wih2, const float* __restrict__ Whh2,
                                const float* __restrict__ bih1, const float* __restrict__ bhh1,
                                const float* __restrict__ bih2, const float* __restrict__ bhh2,
                                bf16* __restrict__ Wc1, bf16* __restrict__ Wc2,
                                float* __restrict__ Bp1, float* __restrict__ Bp2) {
    int idx = blockIdx.x * 256 + threadIdx.x;
    const int n1 = NG * K1;   // 1,703,936
    const int n2 = NG * K2;   // 2,097,152
    if (idx < n1) {
        int n = idx / K1, k = idx - n * K1;
        int on = ((n >> 4) & 3) * RNN + (n >> 6) * 16 + (n & 15);
        float v = 0.f;
        if (k < EMB)        v = Wih1[on * EMB + k];
        else if (k >= EMBP) v = Whh1[on * RNN + (k - EMBP)];
        Wc1[tidx(n, k, K132)] = __float2bfloat16(v);
    }
    if (idx < n2) {
        int n = idx >> 10, k = idx & (K2 - 1);
        int on = ((n >> 4) & 3) * RNN + (n >> 6) * 16 + (n & 15);
        float v = (k < RNN) ? Wih2[on * RNN + k] : Whh2[on * RNN + (k - RNN)];
        Wc2[tidx(n, k, K232)] = __float2bfloat16(v);
    }
    if (idx < NG) {
        int on = ((idx >> 4) & 3) * RNN + (idx >> 6) * 16 + (idx & 15);
        Bp1[idx] = bih1[on] + bhh1[on];
        Bp2[idx] = bih2[on] + bhh2[on];
    }
}

// ---------------------------------------------------------------------------
// Embedding gather + tanh for one timestep -> x-slot (cols 0..319, pad
// zeroed) of the layer-1 A-concat buffer Ac1 (TILED, K32=26).
// ---------------------------------------------------------------------------
__global__ void embed_step(const int* __restrict__ sent, const float* __restrict__ w2v,
                           bf16* __restrict__ Ac1, int t) {
    int row = blockIdx.x;
    int col = threadIdx.x;                 // 0..319
    int id  = sent[row * TSTEPS + t];
    float v = (col < EMB) ? tanhf_(w2v[id * EMB + col]) : 0.f;
    Ac1[tidx(row, col, K132)] = __float2bfloat16(v);
}

// ---------------------------------------------------------------------------
// Fused GEMM + LSTM cell update — ZERO LDS, ZERO BARRIERS.
//   gates[M,2048] = A[M,K] * W[2048,K]^T  (bf16 MFMA 16x16x32, fp32 acc)
// A and W are in TILED fragment layout: each fragment = one coalesced 16B/lane
// global load, straight to VGPRs. No staging, no __syncthreads; latency hidden
// by 16 waves/CU pure TLP (m114). Per (row,unit): c'=sig(f)*c+sig(i)*tanh(g);
// h=sig(o)*tanh(c'). Weight permutation => acc[i][0..3][rr] = gates i,f,g,o
// of one (row,unit) in a single thread — no cross-lane epilogue exchange.
// Block 256 thr = 4 waves; tile 128x128; wave = 64x64 = 4x4 MFMA tiles.
// Grid (16,100), bn fastest => concurrent blocks share A row-tiles in L1/L2.
// ---------------------------------------------------------------------------
#define BM 128
#define BN 128

__global__ __launch_bounds__(256, 4) void gemm_lstm(const bf16* __restrict__ A,
                                                    const bf16* __restrict__ W,
                                                    const float* __restrict__ Bp,
                                                    float* __restrict__ cst,
                                                    bf16* __restrict__ hdst1, int ld32_1, int off1,
                                                    bf16* __restrict__ hdst2, int ld32_2, int off2, int en2,
                                                    float* __restrict__ outf, int en_out,
                                                    int K32) {
    const int tid  = threadIdx.x;
    const int lane = tid & 63;
    const int wave = tid >> 6;
    const int wm   = wave >> 1, wn = wave & 1;
    const int bn   = blockIdx.x;           // 16  (gate-col blocks)
    const int bm   = blockIdx.y;           // 100 (row blocks)

    f32x4 acc[4][4];
#pragma unroll
    for (int i = 0; i < 4; ++i)
#pragma unroll
        for (int j = 0; j < 4; ++j)
#pragma unroll
            for (int r = 0; r < 4; ++r) acc[i][j][r] = 0.f;

    const int r = lane & 15, q = lane >> 4;

    // Fragment base pointers: tile-row bases for this wave's 4 m-tiles /
    // 4 n-tiles; per k-step kt, fragment (i) sits at +(i*K32+kt)*512 elems.
    const bf16* Ab = A + ((size_t)(bm * 8 + wm * 4) * K32 << 9) + lane * 8;
    const bf16* Wb = W + ((size_t)(bn * 8 + wn * 4) * K32 << 9) + lane * 8;

    for (int kt = 0; kt < K32; ++kt) {
        bf16x8 af[4], wf[4];
#pragma unroll
        for (int i = 0; i < 4; ++i)
            af[i] = *(const bf16x8*)(Ab + ((i * K32 + kt) << 9));
#pragma unroll
        for (int j = 0; j < 4; ++j)
            wf[j] = *(const bf16x8*)(Wb + ((j * K32 + kt) << 9));
#pragma unroll
        for (int i = 0; i < 4; ++i)
#pragma unroll
            for (int j = 0; j < 4; ++j)
                acc[i][j] = __builtin_amdgcn_mfma_f32_16x16x32_bf16(
                    af[i], wf[j], acc[i][j], 0, 0, 0);
    }

    // ---- fused LSTM epilogue ----
    // C/D mapping (m89/m91-verified): col = lane&15, row = (lane>>4)*4 + reg
    const int colb = bn * BN + wn * 64;           // this wave's first gate col
    const int u    = (2 * bn + wn) * 16 + r;      // global unit index 0..511
    const float bi = Bp[colb + r];
    const float bf = Bp[colb + 16 + r];
    const float bg = Bp[colb + 32 + r];
    const float bo = Bp[colb + 48 + r];

    // tiled-store offsets for the h destinations (col fixed per thread)
    const int c1c = off1 + u;
    const int w1  = (((c1c >> 3) & 3) << 7) + ((c1c & 7));      // + (row&15)*8 later
    const int t1c = c1c >> 5;
    const int c2c = off2 + u;
    const int w2  = (((c2c >> 3) & 3) << 7) + ((c2c & 7));
    const int t2c = c2c >> 5;

#pragma unroll
    for (int i = 0; i < 4; ++i) {
        const int trow = bm * 8 + wm * 4 + i;     // global 16-row tile index
#pragma unroll
        for (int rr = 0; rr < 4; ++rr) {
            int rlow = q * 4 + rr;                // row within 16-tile
            int row  = trow * 16 + rlow;
            size_t cidx = (size_t)row * RNN + u;
            float gi = acc[i][0][rr] + bi;
            float gf = acc[i][1][rr] + bf;
            float gg = acc[i][2][rr] + bg;
            float go = acc[i][3][rr] + bo;
            float cn = sigmoidf_(gf) * cst[cidx] + sigmoidf_(gi) * tanhf_(gg);
            float h  = sigmoidf_(go) * tanhf_(cn);
            cst[cidx] = cn;
            bf16 hb = __float2bfloat16(h);
            hdst1[(((size_t)trow * ld32_1 + t1c) << 9) + w1 + (rlow << 3)] = hb;
            if (en2)    hdst2[(((size_t)trow * ld32_2 + t2c) << 9) + w2 + (rlow << 3)] = hb;
            if (en_out) outf[cidx] = h;
        }
    }
}

// ---------------------------------------------------------------------------
// Workspace layout (all 16B-aligned; total 107,560,960 B):
//   c1  fp32 [12800][512] linear     26,214,400
//   c2  fp32 [12800][512] linear     26,214,400
//   A2  bf16 tiled K32=32            26,214,400   ([h1|h2] for layer-2 GEMM)
//   Ac1 bf16 tiled K32=26            21,299,200   ([x_t(pad)|h1] for layer-1)
//   Wc1 bf16 tiled K32=26             3,407,872
//   Wc2 bf16 tiled K32=32             4,194,304
//   Bp1 fp32 [2048]                       8,192
//   Bp2 fp32 [2048]                       8,192
// First 99,942,400 B (c1,c2,A2,Ac1) must be zero at t=0 -> one memsetAsync.
// ---------------------------------------------------------------------------
extern "C" void kernel_launch(void* const* d_in, const int* in_sizes, int n_in,
                              void* d_out, int out_size, void* d_ws, size_t ws_size,
                              hipStream_t stream) {
    (void)in_sizes; (void)n_in; (void)out_size; (void)ws_size;
    const int*   sent = (const int*)d_in[0];
    const float* w2v  = (const float*)d_in[1];
    const float* Wih1 = (const float*)d_in[2];
    const float* Whh1 = (const float*)d_in[3];
    const float* bih1 = (const float*)d_in[4];
    const float* bhh1 = (const float*)d_in[5];
    const float* Wih2 = (const float*)d_in[6];
    const float* Whh2 = (const float*)d_in[7];
    const float* bih2 = (const float*)d_in[8];
    const float* bhh2 = (const float*)d_in[9];
    float* out = (float*)d_out;

    char* ws = (char*)d_ws;
    float* c1  = (float*)(ws);
    float* c2  = (float*)(ws + 26214400);
    bf16*  A2  = (bf16*) (ws + 52428800);
    bf16*  Ac1 = (bf16*) (ws + 78643200);
    bf16*  Wc1 = (bf16*) (ws + 99942400);
    bf16*  Wc2 = (bf16*) (ws + 103350272);
    float* Bp1 = (float*)(ws + 107544576);
    float* Bp2 = (float*)(ws + 107552768);

    // zero h/c state + A-buffers (ws is re-poisoned 0xAA before every call)
    hipMemsetAsync(ws, 0, 99942400, stream);

    convert_weights<<<dim3((NG * K2 + 255) / 256), dim3(256), 0, stream>>>(
        Wih1, Whh1, Wih2, Whh2, bih1, bhh1, bih2, bhh2, Wc1, Wc2, Bp1, Bp2);

    for (int t = 0; t < TSTEPS; ++t) {
        // x_t -> Ac1 cols [0,320); h1(t-1) already sits in cols [320,832)
        embed_step<<<dim3(BROWS), dim3(EMBP), 0, stream>>>(sent, w2v, Ac1, t);

        // layer 1: gates = [x_t|h1] @ Wc1^T, fused update
        // h1 -> Ac1 h-slot (next step) and A2 cols [0,512) (this step)
        gemm_lstm<<<dim3(NG / BN, BROWS / BM), dim3(256), 0, stream>>>(
            Ac1, Wc1, Bp1, c1,
            Ac1, K132, EMBP,
            A2,  K232, 0, 1,
            (float*)nullptr, 0, K132);

        // layer 2: gates = [h1|h2] @ Wc2^T, fused update
        // h2 -> A2 cols [512,1024) (next step); final step also -> out (fp32)
        gemm_lstm<<<dim3(NG / BN, BROWS / BM), dim3(256), 0, stream>>>(
            A2, Wc2, Bp2, c2,
            A2, K232, RNN,
            (bf16*)nullptr, 0, 0, 0,
            out, (t == TSTEPS - 1) ? 1 : 0, K232);
    }
}

// Round 5
// 1276.931 us; speedup vs baseline: 1.1270x; 1.1270x over previous
//
#include <hip/hip_runtime.h>
#include <hip/hip_bf16.h>

// Problem constants (from reference): B=64, NCLS=200 -> BN rows = 12800
#define BROWS  12800
#define TSTEPS 8
#define EMB    300
#define EMBP   320          // EMB padded to /32 for MFMA K
#define RNN    512
#define NG     2048         // 4*RNN gate width
#define K1     832          // EMBP + RNN  (layer-1 concat GEMM K), 13*64
#define K132   26
#define K2     1024         // RNN + RNN   (layer-2 concat GEMM K), 16*64
#define K232   32

typedef short bf16x8 __attribute__((ext_vector_type(8)));   // 8 bf16 in 4 VGPRs (m89-verified operand type)
typedef float f32x4  __attribute__((ext_vector_type(4)));
typedef __hip_bfloat16 bf16;

__device__ __forceinline__ float sigmoidf_(float x) { return 1.f / (1.f + __expf(-x)); }
// exp-based tanh: exact saturation at +-inf, ~ulp-level error vs tanhf, one v_exp
__device__ __forceinline__ float tanhf_(float x)    { return 1.f - 2.f / (__expf(2.f * x) + 1.f); }

// async global->LDS, 16B per lane (m97). LDS dest = wave-uniform base + lane*16.
__device__ __forceinline__ void gl_lds16(const bf16* g, bf16* l) {
    __builtin_amdgcn_global_load_lds(
        (const __attribute__((address_space(1))) void*)g,
        (__attribute__((address_space(3))) void*)l,
        16, 0, 0);
}

// ---------------------------------------------------------------------------
// TILED WEIGHT LAYOUT (MFMA-fragment order, round-4 proven): a [16 x 32]
// subtile stored as 512 contiguous bf16 so lane l=16q+r reads its 8 elements
// [n=r][k=q*8+j] at byte l*16. One fragment = one coalesced 1KB wave load.
// T(row,col,K32) = ((row>>4)*K32 + (col>>5))*512 + ((col>>3)&3)*128
//                  + (row&15)*8 + (col&7)
// ---------------------------------------------------------------------------
__device__ __forceinline__ int tidx(int row, int col, int K32) {
    return (((row >> 4) * K32 + (col >> 5)) << 9) + (((col >> 3) & 3) << 7)
           + ((row & 15) << 3) + (col & 7);
}

// ---------------------------------------------------------------------------
// Weight repack: fp32 -> bf16, K-concat, GATE-INTERLEAVED row permutation
// (output row n: w=n&15 unit, g=(n>>4)&3 gate i/f/g/o, b=n>>6 unit group;
// original row = g*512 + b*16 + w), stored TILED. Emits permuted combined
// biases Bp = bih+bhh.
// ---------------------------------------------------------------------------
__global__ void convert_weights(const float* __restrict__ Wih1, const float* __restrict__ Whh1,
                                const float* __restrict__ Wih2, const float* __restrict__ Whh2,
                                const float* __restrict__ bih1, const float* __restrict__ bhh1,
                                const float* __restrict__ bih2, const float* __restrict__ bhh2,
                                bf16* __restrict__ Wc1, bf16* __restrict__ Wc2,
                                float* __restrict__ Bp1, float* __restrict__ Bp2) {
    int idx = blockIdx.x * 256 + threadIdx.x;
    const int n1 = NG * K1;   // 1,703,936
    const int n2 = NG * K2;   // 2,097,152
    if (idx < n1) {
        int n = idx / K1, k = idx - n * K1;
        int on = ((n >> 4) & 3) * RNN + (n >> 6) * 16 + (n & 15);
        float v = 0.f;
        if (k < EMB)        v = Wih1[on * EMB + k];
        else if (k >= EMBP) v = Whh1[on * RNN + (k - EMBP)];
        Wc1[tidx(n, k, K132)] = __float2bfloat16(v);
    }
    if (idx < n2) {
        int n = idx >> 10, k = idx & (K2 - 1);
        int on = ((n >> 4) & 3) * RNN + (n >> 6) * 16 + (n & 15);
        float v = (k < RNN) ? Wih2[on * RNN + k] : Whh2[on * RNN + (k - RNN)];
        Wc2[tidx(n, k, K232)] = __float2bfloat16(v);
    }
    if (idx < NG) {
        int on = ((idx >> 4) & 3) * RNN + (idx >> 6) * 16 + (idx & 15);
        Bp1[idx] = bih1[on] + bhh1[on];
        Bp2[idx] = bih2[on] + bhh2[on];
    }
}

// ---------------------------------------------------------------------------
// Embedding gather + tanh -> x-slot (cols 0..319, pad zeroed) of the
// LINEAR layer-1 A-concat buffer Ac1 [BROWS][K1].
// ---------------------------------------------------------------------------
__global__ void embed_step(const int* __restrict__ sent, const float* __restrict__ w2v,
                           bf16* __restrict__ Ac1, int t) {
    int row = blockIdx.x;
    int col = threadIdx.x;                 // 0..319
    int id  = sent[row * TSTEPS + t];
    float v = (col < EMB) ? tanhf_(w2v[id * EMB + col]) : 0.f;
    Ac1[(size_t)row * K1 + col] = __float2bfloat16(v);
}

// ---------------------------------------------------------------------------
// Fused GEMM + LSTM cell update, hybrid staging:
//   A (activations, linear [M][K]) -> LDS via global_load_lds w=16, XOR chunk
//     swizzle (round-3 proven, zero bank conflicts).
//   W (weights, TILED fragment layout) -> direct global_load_dwordx4 per
//     fragment. W is 4 MB total => resident in every XCD's L2; all 100
//     bm-blocks reuse it, so no reuse is lost by skipping LDS (round-4's
//     mistake was doing this for A too). Halves LDS traffic + barrier-drained
//     vmcnt queue; LDS/block 16 KB.
// Epilogue: per (row,unit) c'=sig(f)*c+sig(i)*tanh(g); h=sig(o)*tanh(c');
// h routed through an LDS transpose (reusing staging buffer) for full-line
// coalesced global stores. Weight permutation => acc[i][0..3][rr] = gates
// i,f,g,o of one (row,unit) in one thread.
// Block 256 thr = 4 waves; tile 128x128 (32 h-units); wave 64x64.
// Grid (16,100), bn fastest => concurrent blocks share A row-tiles in L2.
// ---------------------------------------------------------------------------
#define BM 128
#define BN 128

__global__ __launch_bounds__(256, 4) void gemm_lstm(const bf16* __restrict__ A,
                                                    const bf16* __restrict__ W,
                                                    const float* __restrict__ Bp,
                                                    float* __restrict__ cst,
                                                    bf16* __restrict__ hdst1, int ld1, int off1,
                                                    bf16* __restrict__ hdst2, int ld2, int off2, int en2,
                                                    float* __restrict__ outf, int en_out,
                                                    int K) {
    // 16 KB: A staging [128][64] unpadded (lane-order constraint);
    // reused after the K-loop as h transpose buffer [128][48] (12 KB).
    __shared__ __attribute__((aligned(16))) bf16 smem[BM * 64];

    const int tid  = threadIdx.x;
    const int lane = tid & 63;
    const int wave = tid >> 6;
    const int wm   = wave >> 1, wn = wave & 1;
    const int bn   = blockIdx.x;           // 16  (gate-col blocks)
    const int bm   = blockIdx.y;           // 100 (row blocks)
    const int K32  = K >> 5;

    f32x4 acc[4][4];
#pragma unroll
    for (int i = 0; i < 4; ++i)
#pragma unroll
        for (int j = 0; j < 4; ++j)
#pragma unroll
            for (int r = 0; r < 4; ++r) acc[i][j][r] = 0.f;

    const int r = lane & 15, q = lane >> 4;

    // A staging geometry: chunk ch = c*256+tid; row = ch>>3;
    // global k-chunk = (ch&7)^(row&7)  (XOR swizzle, zero conflicts).
    int srow[4], scol[4];
#pragma unroll
    for (int c = 0; c < 4; ++c) {
        int ch = c * 256 + tid;
        srow[c] = ch >> 3;
        scol[c] = ((ch & 7) ^ (srow[c] & 7)) * 8;
    }
    const bf16* Abase = A + (size_t)(bm * BM) * K;
    // W fragment base: this wave's 4 n-tiles start at tile-row bn*8 + wn*4
    const bf16* Wb = W + ((size_t)(bn * 8 + wn * 4) * K32 << 9) + lane * 8;

    for (int kb = 0; kb < K; kb += 64) {
#pragma unroll
        for (int c = 0; c < 4; ++c) {
            int ch = c * 256 + tid;
            gl_lds16(Abase + (size_t)srow[c] * K + kb + scol[c], &smem[ch * 8]);
        }
        __syncthreads();
#pragma unroll
        for (int kk = 0; kk < 64; kk += 32) {
            const int kt = (kb + kk) >> 5;
            const int kc = kk >> 3;        // 0 or 4
            bf16x8 af[4], wf[4];
#pragma unroll
            for (int i = 0; i < 4; ++i)
                af[i] = *(const bf16x8*)(&smem[(wm * 64 + i * 16 + r) * 64 + (((q + kc) ^ (r & 7)) * 8)]);
#pragma unroll
            for (int j = 0; j < 4; ++j)
                wf[j] = *(const bf16x8*)(Wb + ((j * K32 + kt) << 9));
#pragma unroll
            for (int i = 0; i < 4; ++i)
#pragma unroll
                for (int j = 0; j < 4; ++j)
                    acc[i][j] = __builtin_amdgcn_mfma_f32_16x16x32_bf16(
                        af[i], wf[j], acc[i][j], 0, 0, 0);
        }
        __syncthreads();
    }
    // trailing __syncthreads: all smem reads done -> safe to reuse as hbuf

    // ---- fused LSTM epilogue ----
    // C/D mapping (m89/m91-verified): col = lane&15, row = (lane>>4)*4 + reg
    const int colb = bn * BN + wn * 64;
    const int u    = (2 * bn + wn) * 16 + r;      // global unit index 0..511
    const float bi = Bp[colb + r];
    const float bf = Bp[colb + 16 + r];
    const float bg = Bp[colb + 32 + r];
    const float bo = Bp[colb + 48 + r];

    // hoist the 16 scattered c-loads so they overlap the math below
    float cc[4][4];
#pragma unroll
    for (int i = 0; i < 4; ++i)
#pragma unroll
        for (int rr = 0; rr < 4; ++rr) {
            int row = bm * BM + wm * 64 + i * 16 + q * 4 + rr;
            cc[i][rr] = cst[(size_t)row * RNN + u];
        }

#define HLD 48   // hbuf row stride (96 B: 16B-aligned for b128, 24-bank shift)
#pragma unroll
    for (int i = 0; i < 4; ++i) {
#pragma unroll
        for (int rr = 0; rr < 4; ++rr) {
            int rowl = wm * 64 + i * 16 + q * 4 + rr;       // row in block
            int row  = bm * BM + rowl;
            size_t cidx = (size_t)row * RNN + u;
            float gi = acc[i][0][rr] + bi;
            float gf = acc[i][1][rr] + bf;
            float gg = acc[i][2][rr] + bg;
            float go = acc[i][3][rr] + bo;
            float cn = sigmoidf_(gf) * cc[i][rr] + sigmoidf_(gi) * tanhf_(gg);
            float h  = sigmoidf_(go) * tanhf_(cn);
            cst[cidx] = cn;                                  // 64B-coalesced
            if (en_out) outf[cidx] = h;                      // 64B-coalesced
            // h -> transpose buffer; col-in-block = wn*16 + r (0..31)
            smem[rowl * HLD + wn * 16 + r] = __float2bfloat16(h);
        }
    }
    __syncthreads();

    // coalesced h stores: 128 rows x 32 units bf16 = 4096 elems; 8/thread/half
#pragma unroll
    for (int half = 0; half < 2; ++half) {
        int t    = half * 256 + tid;       // 0..511
        int rowl = t >> 2;                 // 0..127
        int c8   = (t & 3) * 8;            // 0,8,16,24
        uint4 v  = *(const uint4*)&smem[rowl * HLD + c8];
        int row  = bm * BM + rowl;
        int gcol = bn * 32 + c8;           // unit col within [0,512)
        *(uint4*)&hdst1[(size_t)row * ld1 + off1 + gcol] = v;
        if (en2) *(uint4*)&hdst2[(size_t)row * ld2 + off2 + gcol] = v;
    }
#undef HLD
}

// ---------------------------------------------------------------------------
// Workspace layout (all 16B-aligned; total 107,560,960 B):
//   c1  fp32 [12800][512] linear     26,214,400
//   c2  fp32 [12800][512] linear     26,214,400
//   A2  bf16 [12800][1024] linear    26,214,400   ([h1|h2] for layer-2 GEMM)
//   Ac1 bf16 [12800][832] linear     21,299,200   ([x_t(pad)|h1] for layer-1)
//   Wc1 bf16 tiled K32=26             3,407,872
//   Wc2 bf16 tiled K32=32             4,194,304
//   Bp1 fp32 [2048]                       8,192
//   Bp2 fp32 [2048]                       8,192
// First 99,942,400 B (c1,c2,A2,Ac1) must be zero at t=0 -> one memsetAsync.
// ---------------------------------------------------------------------------
extern "C" void kernel_launch(void* const* d_in, const int* in_sizes, int n_in,
                              void* d_out, int out_size, void* d_ws, size_t ws_size,
                              hipStream_t stream) {
    (void)in_sizes; (void)n_in; (void)out_size; (void)ws_size;
    const int*   sent = (const int*)d_in[0];
    const float* w2v  = (const float*)d_in[1];
    const float* Wih1 = (const float*)d_in[2];
    const float* Whh1 = (const float*)d_in[3];
    const float* bih1 = (const float*)d_in[4];
    const float* bhh1 = (const float*)d_in[5];
    const float* Wih2 = (const float*)d_in[6];
    const float* Whh2 = (const float*)d_in[7];
    const float* bih2 = (const float*)d_in[8];
    const float* bhh2 = (const float*)d_in[9];
    float* out = (float*)d_out;

    char* ws = (char*)d_ws;
    float* c1  = (float*)(ws);
    float* c2  = (float*)(ws + 26214400);
    bf16*  A2  = (bf16*) (ws + 52428800);
    bf16*  Ac1 = (bf16*) (ws + 78643200);
    bf16*  Wc1 = (bf16*) (ws + 99942400);
    bf16*  Wc2 = (bf16*) (ws + 103350272);
    float* Bp1 = (float*)(ws + 107544576);
    float* Bp2 = (float*)(ws + 107552768);

    // zero h/c state + A-buffers (ws is re-poisoned 0xAA before every call)
    hipMemsetAsync(ws, 0, 99942400, stream);

    convert_weights<<<dim3((NG * K2 + 255) / 256), dim3(256), 0, stream>>>(
        Wih1, Whh1, Wih2, Whh2, bih1, bhh1, bih2, bhh2, Wc1, Wc2, Bp1, Bp2);

    for (int t = 0; t < TSTEPS; ++t) {
        // x_t -> Ac1 cols [0,320); h1(t-1) already sits in cols [320,832)
        embed_step<<<dim3(BROWS), dim3(EMBP), 0, stream>>>(sent, w2v, Ac1, t);

        // layer 1: gates = [x_t|h1] @ Wc1^T, fused update
        // h1 -> Ac1 h-slot (next step) and A2 cols [0,512) (this step)
        gemm_lstm<<<dim3(NG / BN, BROWS / BM), dim3(256), 0, stream>>>(
            Ac1, Wc1, Bp1, c1,
            Ac1, K1, EMBP,
            A2,  K2, 0, 1,
            (float*)nullptr, 0, K1);

        // layer 2: gates = [h1|h2] @ Wc2^T, fused update
        // h2 -> A2 cols [512,1024) (next step); final step also -> out (fp32)
        gemm_lstm<<<dim3(NG / BN, BROWS / BM), dim3(256), 0, stream>>>(
            A2, Wc2, Bp2, c2,
            A2, K2, RNN,
            (bf16*)nullptr, 0, 0, 0,
            out, (t == TSTEPS - 1) ? 1 : 0, K2);
    }
}